// Round 1
// baseline (21799.904 us; speedup 1.0000x reference)
//
#include <hip/hip_runtime.h>
#include <cstdint>
#include <cstddef>

typedef unsigned short u16;
typedef __attribute__((ext_vector_type(8))) short s16x8;
typedef __attribute__((ext_vector_type(4))) float f32x4;
typedef __attribute__((ext_vector_type(4))) unsigned short u16x4;

#define AGENT __HIP_MEMORY_SCOPE_AGENT

namespace {
constexpr int NWG  = 256;
constexpr int NTHR = 256;
constexpr int Bb   = 256;   // batch
constexpr int Tt   = 256;   // timesteps
constexpr int EMB_ = 256;
constexpr int HID_ = 512;
constexpr int NCLS = 32000;

// ---- LDS layout (dynamic smem, bytes) ----
constexpr int W1S = 776;    // padded stride (elems) for stage1 [32 cols][768 k]
constexpr int W2S = 1032;   // stage2 [16 cols][1024 k]
constexpr int WFS = 520;    // final  [128 cols][512 k]
constexpr int OFF_W1 = 0;
constexpr int OFF_W3 = OFF_W1 + 32 * W1S * 2;  // 49664
constexpr int OFF_W2 = OFF_W3 + 32 * W1S * 2;  // 99328 (+33024 = 132352)
constexpr int OFF_DS = 133120;                 // Dscr [64][33] f32; also >= final Wf end (128*520*2=133120)
constexpr int OFF_C  = OFF_DS + 64 * 33 * 4;   // 141568  (C state [64][8] f32; bq reuse in final)
constexpr int OFF_C1 = OFF_C + 64 * 8 * 4;     // 143616
constexpr int OFF_B1 = OFF_C1 + 64 * 8 * 4;    // 145664
constexpr int OFF_B3 = OFF_B1 + 128;
constexpr int OFF_B2 = OFF_B3 + 128;
constexpr int SMEM_BYTES = OFF_B2 + 64;        // 145984  (>80KB -> exactly 1 WG/CU)

// ---- workspace layout (bytes) ----
constexpr size_t WS_HB0 = 256;                         // H buffer parity 0, [B][512] bf16
constexpr size_t WS_HB1 = WS_HB0 + (size_t)Bb * HID_ * 2;
constexpr size_t WS_H1  = WS_HB1 + (size_t)Bb * HID_ * 2;   // H1 state
constexpr size_t WS_HM  = WS_H1 + (size_t)Bb * HID_ * 2;    // H1mix
constexpr size_t WS_XE  = WS_HM + (size_t)Bb * HID_ * 2;    // Xe [T][B][EMB] bf16 (33.5 MB)
}  // namespace

struct Params {
  const int* X; const float* Hin; const float* Cin; const float* E;
  const float* Wx[4];  const float* Wh[4];  const float* bg[4];   // cell 1 (i,f,o,c)
  const float* Wx1[4]; const float* Wh1[4]; const float* bg1[4];  // cell 2
  const float* Wxh; const float* Whh; const float* bh;
  const float* Whq; const float* bq;
  float* out; char* ws;
};

__device__ __forceinline__ u16 f2bf(float f) {
  union { float f; unsigned u; } v; v.f = f;
  unsigned r = v.u + 0x7FFFu + ((v.u >> 16) & 1u);
  return (u16)(r >> 16);
}
__device__ __forceinline__ float sigm(float x) { return 1.f / (1.f + __expf(-x)); }
__device__ __forceinline__ float tanh_(float x) {
  x = fminf(fmaxf(x, -10.f), 10.f);
  float e = __expf(-2.f * x);
  return (1.f - e) / (1.f + e);
}
__device__ __forceinline__ f32x4 mfma16(s16x8 a, s16x8 b, f32x4 c) {
  return __builtin_amdgcn_mfma_f32_16x16x32_bf16(a, b, c, 0, 0, 0);
}

// device-scope grid barrier: ctrl[0]=count, ctrl[1]=generation
__device__ __forceinline__ void gridbar(unsigned* ctrl, unsigned target) {
  __syncthreads();
  if (threadIdx.x == 0) {
    unsigned old = __hip_atomic_fetch_add(&ctrl[0], 1u, __ATOMIC_ACQ_REL, AGENT);
    if (old == NWG - 1) {
      __hip_atomic_store(&ctrl[0], 0u, __ATOMIC_RELAXED, AGENT);
      __hip_atomic_store(&ctrl[1], target, __ATOMIC_RELEASE, AGENT);
    } else {
      while (__hip_atomic_load(&ctrl[1], __ATOMIC_ACQUIRE, AGENT) < target)
        __builtin_amdgcn_s_sleep(1);
    }
  }
  __syncthreads();
}

// One LSTM-cell phase: gates = [x_t | Hrec] @ Wlds (+bias) -> elementwise -> Hdst chunk.
// WG (g,c) computes rows g*64..+63, HID slice c*8..+7 for all 4 gates (N=32 cols).
__device__ __forceinline__ void cell_phase(char* smem, int offW, int offB, int offC,
                                           const u16* Xt, const u16* Hrec, u16* Hdst,
                                           int g, int c, int w, int lane, int tid) {
  const int r = lane & 15, q = lane >> 4;
  const int row0 = w * 16;
  const u16* xrow = Xt + (size_t)(g * 64 + row0 + r) * EMB_;
  const u16* hrow = Hrec + (size_t)(g * 64 + row0 + r) * HID_;
  const u16* wb = (const u16*)(smem + offW);
  f32x4 acc0 = {0.f, 0.f, 0.f, 0.f}, acc1 = {0.f, 0.f, 0.f, 0.f};
#pragma unroll
  for (int k0 = 0; k0 < 256; k0 += 32) {              // x_t part of K
    int kk = k0 + q * 8;
    s16x8 a  = *(const s16x8*)(xrow + kk);
    s16x8 b0 = *(const s16x8*)(wb + (size_t)r * W1S + kk);
    s16x8 b1 = *(const s16x8*)(wb + (size_t)(16 + r) * W1S + kk);
    acc0 = mfma16(a, b0, acc0);
    acc1 = mfma16(a, b1, acc1);
  }
#pragma unroll
  for (int k0 = 0; k0 < 512; k0 += 32) {              // recurrent part of K
    int kk = k0 + q * 8;
    s16x8 a  = *(const s16x8*)(hrow + kk);
    s16x8 b0 = *(const s16x8*)(wb + (size_t)r * W1S + 256 + kk);
    s16x8 b1 = *(const s16x8*)(wb + (size_t)(16 + r) * W1S + 256 + kk);
    acc0 = mfma16(a, b0, acc0);
    acc1 = mfma16(a, b1, acc1);
  }
  float* Ds = (float*)(smem + OFF_DS);
#pragma unroll
  for (int i = 0; i < 4; i++) {
    Ds[(row0 + q * 4 + i) * 33 + r]      = acc0[i];
    Ds[(row0 + q * 4 + i) * 33 + 16 + r] = acc1[i];
  }
  __syncthreads();
  const float* bs = (const float*)(smem + offB);
  float* Cs = (float*)(smem + offC);
#pragma unroll
  for (int it = 0; it < 2; it++) {
    int idx = tid + it * 256;          // 512 items = 64 rows x 8 hid
    int row = idx >> 3, j = idx & 7;
    float vi = Ds[row * 33 + 0 + j]  + bs[0 + j];
    float vf = Ds[row * 33 + 8 + j]  + bs[8 + j];
    float vo = Ds[row * 33 + 16 + j] + bs[16 + j];
    float vc = Ds[row * 33 + 24 + j] + bs[24 + j];
    float I = sigm(vi), F = sigm(vf), O = sigm(vo), Ct = tanh_(vc);
    float Cn = F * Cs[row * 8 + j] + I * Ct;
    Cs[row * 8 + j] = Cn;
    float Hn = O * tanh_(Cn);
    Hdst[(size_t)(g * 64 + row) * HID_ + c * 8 + j] = f2bf(Hn);
  }
}

__global__ __launch_bounds__(NTHR, 1) void lstm_pers(Params p) {
  extern __shared__ char smem[];
  const int tid = threadIdx.x;
  const int bi = blockIdx.x;
  const int w = tid >> 6, lane = tid & 63;
  const int g = bi >> 6, c = bi & 63;
  const int r = lane & 15, q = lane >> 4;

  unsigned* ctrl = (unsigned*)p.ws;
  u16* Hb0 = (u16*)(p.ws + WS_HB0);
  u16* Hb1 = (u16*)(p.ws + WS_HB1);
  u16* H1b = (u16*)(p.ws + WS_H1);
  u16* H1m = (u16*)(p.ws + WS_HM);
  u16* Xe  = (u16*)(p.ws + WS_XE);

  if (bi == 0 && tid == 0) {   // barrier-state init + magic handshake
    __hip_atomic_store(&ctrl[0], 0u, __ATOMIC_RELAXED, AGENT);
    __hip_atomic_store(&ctrl[1], 0u, __ATOMIC_RELAXED, AGENT);
    __hip_atomic_store(&ctrl[2], 0xC0FFEEu, __ATOMIC_RELEASE, AGENT);
  }

  // ---- one-time init: weights -> LDS (bf16, transposed [col][k]) ----
  {
    u16* w1 = (u16*)(smem + OFF_W1);
    u16* w3 = (u16*)(smem + OFF_W3);
    int gate = tid >> 6, kk8 = (tid >> 3) & 7, j = tid & 7;
    int hid = c * 8 + j;
    for (int k0 = 0; k0 < 256; k0 += 8) {
      int k = k0 + kk8;
      w1[(size_t)(gate * 8 + j) * W1S + k] = f2bf(p.Wx[gate][(size_t)k * HID_ + hid]);
      w3[(size_t)(gate * 8 + j) * W1S + k] = f2bf(p.Wx1[gate][(size_t)k * HID_ + hid]);
    }
    for (int k0 = 0; k0 < 512; k0 += 8) {
      int k = k0 + kk8;
      w1[(size_t)(gate * 8 + j) * W1S + 256 + k] = f2bf(p.Wh[gate][(size_t)k * HID_ + hid]);
      w3[(size_t)(gate * 8 + j) * W1S + 256 + k] = f2bf(p.Wh1[gate][(size_t)k * HID_ + hid]);
    }
    if (c < 32) {
      u16* w2 = (u16*)(smem + OFF_W2);
      int kk16 = tid >> 4, j2 = tid & 15;
      int hid2 = c * 16 + j2;
      for (int k0 = 0; k0 < 512; k0 += 16) {
        int k = k0 + kk16;
        w2[(size_t)j2 * W2S + k]       = f2bf(p.Wxh[(size_t)k * HID_ + hid2]);
        w2[(size_t)j2 * W2S + 512 + k] = f2bf(p.Whh[(size_t)k * HID_ + hid2]);
      }
      if (tid < 16) ((float*)(smem + OFF_B2))[tid] = p.bh[c * 16 + tid];
    }
    if (tid < 32) {
      int gt = tid >> 3, jj = tid & 7;
      ((float*)(smem + OFF_B1))[tid] = p.bg[gt][c * 8 + jj];
      ((float*)(smem + OFF_B3))[tid] = p.bg1[gt][c * 8 + jj];
    }
    // C / C1 state (fp32, LDS-resident, WG-local forever)
    float* Cs = (float*)(smem + OFF_C);
    float* C1s = (float*)(smem + OFF_C1);
    for (int it = 0; it < 2; it++) {
      int idx = tid + it * 256;
      int row = idx >> 3, j8 = idx & 7;
      float v = p.Cin[(size_t)(g * 64 + row) * HID_ + c * 8 + j8];
      Cs[row * 8 + j8] = v;
      C1s[row * 8 + j8] = v;
    }
  }
  // H / H1 state init (bf16 in ws), 512 elems per WG, coalesced
  for (int it = 0; it < 2; it++) {
    int idx = bi * 512 + tid + it * 256;
    u16 hv = f2bf(p.Hin[idx]);
    Hb0[idx] = hv;
    H1b[idx] = hv;
  }
  // Embedding gather: WG bi handles timestep t=bi; Xe[t][b][:] = bf16(E[X[b][t]])
  {
    const int t0 = bi;
    for (int pp = 0; pp < 64; pp++) {
      int b = w * 64 + pp;
      int tok = p.X[(size_t)b * Tt + t0];
      const float4* er = (const float4*)(p.E + (size_t)tok * EMB_);
      float4 v = er[lane];
      u16x4 u; u.x = f2bf(v.x); u.y = f2bf(v.y); u.z = f2bf(v.z); u.w = f2bf(v.w);
      *(u16x4*)(Xe + ((size_t)t0 * Bb + b) * EMB_ + lane * 4) = u;
    }
  }
  // wait for barrier state to be initialized, then first grid barrier
  if (tid == 0) {
    while (__hip_atomic_load(&ctrl[2], __ATOMIC_ACQUIRE, AGENT) != 0xC0FFEEu)
      __builtin_amdgcn_s_sleep(1);
  }
  __syncthreads();
  unsigned bar = 0;
  gridbar(ctrl, ++bar);

  // ---- recurrent loop ----
  for (int t = 0; t < Tt; t++) {
    const u16* Xt = Xe + (size_t)t * Bb * EMB_;
    u16* Hsrc = (t & 1) ? Hb1 : Hb0;
    u16* Hdst = (t & 1) ? Hb0 : Hb1;

    // phase 1: cell 1  (reads Hsrc, writes Hdst)
    cell_phase(smem, OFF_W1, OFF_B1, OFF_C, Xt, Hsrc, Hdst, g, c, w, lane, tid);
    gridbar(ctrl, ++bar);

    // phase 2: H1mix = sigmoid(Hnew@W_xh + H1old@W_hh + b_h)   (WGs c<32, 16 cols each)
    if (c < 32) {
      const u16* h0 = Hdst + (size_t)(g * 64 + w * 16 + r) * HID_;
      const u16* h1 = H1b + (size_t)(g * 64 + w * 16 + r) * HID_;
      const u16* wb = (const u16*)(smem + OFF_W2);
      f32x4 acc = {0.f, 0.f, 0.f, 0.f};
#pragma unroll
      for (int k0 = 0; k0 < 512; k0 += 32) {
        int kk = k0 + q * 8;
        s16x8 a = *(const s16x8*)(h0 + kk);
        s16x8 b = *(const s16x8*)(wb + (size_t)r * W2S + kk);
        acc = mfma16(a, b, acc);
      }
#pragma unroll
      for (int k0 = 0; k0 < 512; k0 += 32) {
        int kk = k0 + q * 8;
        s16x8 a = *(const s16x8*)(h1 + kk);
        s16x8 b = *(const s16x8*)(wb + (size_t)r * W2S + 512 + kk);
        acc = mfma16(a, b, acc);
      }
      const float* b2 = (const float*)(smem + OFF_B2);
#pragma unroll
      for (int i = 0; i < 4; i++) {
        float v = sigm(acc[i] + b2[r]);
        H1m[(size_t)(g * 64 + w * 16 + q * 4 + i) * HID_ + c * 16 + r] = f2bf(v);
      }
    }
    gridbar(ctrl, ++bar);

    // phase 3: cell 2  (reads H1mix, writes H1b)
    cell_phase(smem, OFF_W3, OFF_B3, OFF_C1, Xt, H1m, H1b, g, c, w, lane, tid);
    gridbar(ctrl, ++bar);
  }

  // ---- final: out = H1 @ W_hq + b_q   (250 WGs x 128 cols) ----
  if (bi < 250) {
    const int n0 = bi * 128;
    u16* Wf = (u16*)smem;   // reuse weight LDS
    for (int idx = tid; idx < 512 * 128; idx += NTHR) {
      int k = idx >> 7, n = idx & 127;
      Wf[(size_t)n * WFS + k] = f2bf(p.Whq[(size_t)k * NCLS + n0 + n]);
    }
    float* bqs = (float*)(smem + OFF_C);
    if (tid < 128) bqs[tid] = p.bq[n0 + tid];
    __syncthreads();
    for (int mt = 0; mt < 4; mt++) {
      int rowb = mt * 64 + w * 16;
      const u16* arow = H1b + (size_t)(rowb + r) * HID_;
      f32x4 acc[8];
#pragma unroll
      for (int nt = 0; nt < 8; nt++) acc[nt] = (f32x4){0.f, 0.f, 0.f, 0.f};
      for (int k0 = 0; k0 < 512; k0 += 32) {
        int kk = k0 + q * 8;
        s16x8 a = *(const s16x8*)(arow + kk);
#pragma unroll
        for (int nt = 0; nt < 8; nt++) {
          s16x8 b = *(const s16x8*)(Wf + (size_t)(nt * 16 + r) * WFS + kk);
          acc[nt] = mfma16(a, b, acc[nt]);
        }
      }
#pragma unroll
      for (int nt = 0; nt < 8; nt++)
#pragma unroll
        for (int i = 0; i < 4; i++)
          p.out[(size_t)(rowb + q * 4 + i) * NCLS + n0 + nt * 16 + r] =
              acc[nt][i] + bqs[nt * 16 + r];
    }
  }
}

extern "C" void kernel_launch(void* const* d_in, const int* in_sizes, int n_in,
                              void* d_out, int out_size, void* d_ws, size_t ws_size,
                              hipStream_t stream) {
  (void)in_sizes; (void)n_in; (void)out_size; (void)ws_size;
  Params p;
  p.X   = (const int*)d_in[0];
  p.Hin = (const float*)d_in[1];
  p.Cin = (const float*)d_in[2];
  p.E   = (const float*)d_in[3];
  for (int gidx = 0; gidx < 4; gidx++) {   // gate order i,f,o,c
    int base = 4 + gidx * 6;
    p.Wx[gidx]  = (const float*)d_in[base + 0];
    p.Wh[gidx]  = (const float*)d_in[base + 1];
    p.bg[gidx]  = (const float*)d_in[base + 2];
    p.Wx1[gidx] = (const float*)d_in[base + 3];
    p.Wh1[gidx] = (const float*)d_in[base + 4];
    p.bg1[gidx] = (const float*)d_in[base + 5];
  }
  p.Wxh = (const float*)d_in[28];
  p.Whh = (const float*)d_in[29];
  p.bh  = (const float*)d_in[30];
  p.Whq = (const float*)d_in[31];
  p.bq  = (const float*)d_in[32];
  p.out = (float*)d_out;
  p.ws  = (char*)d_ws;

  hipFuncSetAttribute(reinterpret_cast<const void*>(lstm_pers),
                      hipFuncAttributeMaxDynamicSharedMemorySize, SMEM_BYTES);
  lstm_pers<<<dim3(NWG), dim3(NTHR), SMEM_BYTES, stream>>>(p);
}

// Round 2
// 14195.428 us; speedup vs baseline: 1.5357x; 1.5357x over previous
//
#include <hip/hip_runtime.h>
#include <cstdint>
#include <cstddef>

typedef unsigned short u16;
typedef __attribute__((ext_vector_type(8))) short s16x8;
typedef __attribute__((ext_vector_type(4))) float f32x4;
typedef __attribute__((ext_vector_type(4))) unsigned short u16x4;

#define AGENT __HIP_MEMORY_SCOPE_AGENT

namespace {
constexpr int NWG  = 256;
constexpr int NTHR = 256;
constexpr int Bb   = 256;   // batch
constexpr int Tt   = 256;   // timesteps
constexpr int EMB_ = 256;
constexpr int HID_ = 512;
constexpr int NCLS = 32000;

// ---- LDS layout (bytes). B-operands stored in MFMA lane order:
//      elem addr = ((kb*NT + n)*64 + lane)*8 + e  -> ds_read_b128 lane-linear, 0 conflicts
constexpr int OFF_W1 = 0;                     // cell1 [24 kb][2 n][64 lane][8] = 49152 B
constexpr int OFF_W3 = 49152;                 // cell2, same shape
constexpr int OFF_W2 = 98304;                 // mix   [32 kb][1 n][64][8]     = 32768 B
constexpr int OFF_DS = 131072;                // gate scratch [64][33] f32 = 8448 B (final Wf = 131072 B reuses [0,131072))
constexpr int OFF_C  = 139520;                // C  state [64][8] f32 (bq reuse in final)
constexpr int OFF_C1 = 141568;                // C1 state
constexpr int OFF_B1 = 143616;
constexpr int OFF_B3 = 143744;
constexpr int OFF_B2 = 143872;
constexpr int SMEM_BYTES = 143936;            // 1 WG/CU

// ---- workspace layout (bytes) ----
constexpr size_t WS_FL   = 0;                         // 4 groups x 64 int flags
constexpr size_t WS_DONE = 1024;                      // 256 int done flags
constexpr size_t WS_HB0  = 2048;                      // H parity 0 [B][512] bf16
constexpr size_t WS_HB1  = WS_HB0 + (size_t)Bb * HID_ * 2;
constexpr size_t WS_H1   = WS_HB1 + (size_t)Bb * HID_ * 2;   // H1 state
constexpr size_t WS_HM   = WS_H1 + (size_t)Bb * HID_ * 2;    // H1mix
constexpr size_t WS_XE   = WS_HM + (size_t)Bb * HID_ * 2;    // Xe [T][B][EMB] bf16
}  // namespace

struct Params {
  const int* X; const float* Hin; const float* Cin; const float* E;
  const float* Wx[4];  const float* Wh[4];  const float* bg[4];   // cell 1 (i,f,o,c)
  const float* Wx1[4]; const float* Wh1[4]; const float* bg1[4];  // cell 2
  const float* Wxh; const float* Whh; const float* bh;
  const float* Whq; const float* bq;
  float* out; char* ws;
};

__device__ __forceinline__ u16 f2bf(float f) {
  union { float f; unsigned u; } v; v.f = f;
  unsigned r = v.u + 0x7FFFu + ((v.u >> 16) & 1u);
  return (u16)(r >> 16);
}
__device__ __forceinline__ float sigm(float x) { return 1.f / (1.f + __expf(-x)); }
__device__ __forceinline__ float tanh_(float x) {
  x = fminf(fmaxf(x, -10.f), 10.f);
  float e = __expf(-2.f * x);
  return (1.f - e) / (1.f + e);
}
__device__ __forceinline__ f32x4 mfma16(s16x8 a, s16x8 b, f32x4 c) {
  return __builtin_amdgcn_mfma_f32_16x16x32_bf16(a, b, c, 0, 0, 0);
}

// Group barrier over 64 WGs: per-WG release-store of monotonic phase number into
// own slot (no RMW), wave-0 polls all 64 slots with RELAXED loads, one acquire
// fence after success. 0xAA-poisoned flags read as negative int -> safe pre-init.
__device__ __forceinline__ void groupbar(int* fl, int slot, int ph) {
  __syncthreads();                       // all waves' data stores drained (vmcnt 0)
  if (threadIdx.x == 0)
    __hip_atomic_store(&fl[slot], ph, __ATOMIC_RELEASE, AGENT);
  if (threadIdx.x < 64) {
    for (;;) {
      int v = __hip_atomic_load(&fl[threadIdx.x], __ATOMIC_RELAXED, AGENT);
      if (!__any(v < ph)) break;
      __builtin_amdgcn_s_sleep(1);
    }
  }
  __syncthreads();
  __builtin_amdgcn_fence(__ATOMIC_ACQUIRE, "agent");
}

// One-time all-grid done wait (only before the final GEMM).
__device__ __forceinline__ void donebar(int* dn, int bi) {
  __syncthreads();
  if (threadIdx.x == 0)
    __hip_atomic_store(&dn[bi], 1, __ATOMIC_RELEASE, AGENT);
  for (;;) {
    int v = __hip_atomic_load(&dn[threadIdx.x], __ATOMIC_RELAXED, AGENT);
    if (!__any(v < 1)) break;
    __builtin_amdgcn_s_sleep(1);
  }
  __syncthreads();
  __builtin_amdgcn_fence(__ATOMIC_ACQUIRE, "agent");
}

// One LSTM-cell phase: gates = [x_t | Hrec] @ Wlds (+bias) -> elementwise -> Hdst chunk.
// WG (g,c) computes rows g*64..+63, HID slice c*8..+7 for all 4 gates (N=32 cols).
__device__ __forceinline__ void cell_phase(char* smem, int offW, int offB, int offC,
                                           const u16* Xt, const u16* Hrec, u16* Hdst,
                                           int g, int c, int w, int lane, int tid) {
  const int r = lane & 15, q = lane >> 4;
  const int row0 = w * 16;
  const u16* xrow = Xt + (size_t)(g * 64 + row0 + r) * EMB_;
  const u16* hrow = Hrec + (size_t)(g * 64 + row0 + r) * HID_;
  const u16* wb = (const u16*)(smem + offW) + lane * 8;
  f32x4 acc0 = {0.f, 0.f, 0.f, 0.f}, acc1 = {0.f, 0.f, 0.f, 0.f};
#pragma unroll
  for (int kb = 0; kb < 8; kb++) {                    // x_t part of K (256)
    s16x8 a  = *(const s16x8*)(xrow + kb * 32 + q * 8);
    s16x8 b0 = *(const s16x8*)(wb + (size_t)(kb * 2 + 0) * 512);
    s16x8 b1 = *(const s16x8*)(wb + (size_t)(kb * 2 + 1) * 512);
    acc0 = mfma16(a, b0, acc0);
    acc1 = mfma16(a, b1, acc1);
  }
#pragma unroll
  for (int kb = 8; kb < 24; kb++) {                   // recurrent part of K (512)
    s16x8 a  = *(const s16x8*)(hrow + (kb - 8) * 32 + q * 8);
    s16x8 b0 = *(const s16x8*)(wb + (size_t)(kb * 2 + 0) * 512);
    s16x8 b1 = *(const s16x8*)(wb + (size_t)(kb * 2 + 1) * 512);
    acc0 = mfma16(a, b0, acc0);
    acc1 = mfma16(a, b1, acc1);
  }
  float* Ds = (float*)(smem + OFF_DS);
#pragma unroll
  for (int i = 0; i < 4; i++) {
    Ds[(row0 + q * 4 + i) * 33 + r]      = acc0[i];
    Ds[(row0 + q * 4 + i) * 33 + 16 + r] = acc1[i];
  }
  __syncthreads();
  const float* bs = (const float*)(smem + offB);
  float* Cs = (float*)(smem + offC);
#pragma unroll
  for (int it = 0; it < 2; it++) {
    int idx = tid + it * 256;          // 512 items = 64 rows x 8 hid
    int row = idx >> 3, j = idx & 7;
    float vi = Ds[row * 33 + 0 + j]  + bs[0 + j];
    float vf = Ds[row * 33 + 8 + j]  + bs[8 + j];
    float vo = Ds[row * 33 + 16 + j] + bs[16 + j];
    float vc = Ds[row * 33 + 24 + j] + bs[24 + j];
    float I = sigm(vi), F = sigm(vf), O = sigm(vo), Ct = tanh_(vc);
    float Cn = F * Cs[row * 8 + j] + I * Ct;
    Cs[row * 8 + j] = Cn;
    float Hn = O * tanh_(Cn);
    Hdst[(size_t)(g * 64 + row) * HID_ + c * 8 + j] = f2bf(Hn);
  }
}

__global__ __launch_bounds__(NTHR, 1) void lstm_pers(Params p) {
  extern __shared__ char smem[];
  const int tid = threadIdx.x;
  const int bi = blockIdx.x;
  const int w = tid >> 6, lane = tid & 63;
  const int g = bi >> 6, c = bi & 63;
  const int r = lane & 15, q = lane >> 4;

  int* fl = (int*)(p.ws + WS_FL) + g * 64;
  int* dn = (int*)(p.ws + WS_DONE);
  u16* Hb0 = (u16*)(p.ws + WS_HB0);
  u16* Hb1 = (u16*)(p.ws + WS_HB1);
  u16* H1b = (u16*)(p.ws + WS_H1);
  u16* H1m = (u16*)(p.ws + WS_HM);
  u16* Xe  = (u16*)(p.ws + WS_XE);

  // ---- one-time init: weights -> LDS (bf16, MFMA lane-order swizzle) ----
  {
    u16* w1 = (u16*)(smem + OFF_W1);
    u16* w3 = (u16*)(smem + OFF_W3);
    int gate = tid >> 6, kk8 = (tid >> 3) & 7, j = tid & 7;
    int cc = gate * 8 + j;          // col 0..31 (i0..7,f0..7,o0..7,c0..7)
    int n = cc >> 4, rr = cc & 15;
    int hid = c * 8 + j;
    for (int kk = kk8; kk < 768; kk += 8) {
      int kb = kk >> 5, q2 = (kk >> 3) & 3, e = kk & 7;
      size_t dst = ((size_t)(kb * 2 + n) * 64 + q2 * 16 + rr) * 8 + e;
      float s1 = (kk < 256) ? p.Wx[gate][(size_t)kk * HID_ + hid]
                            : p.Wh[gate][(size_t)(kk - 256) * HID_ + hid];
      float s3 = (kk < 256) ? p.Wx1[gate][(size_t)kk * HID_ + hid]
                            : p.Wh1[gate][(size_t)(kk - 256) * HID_ + hid];
      w1[dst] = f2bf(s1);
      w3[dst] = f2bf(s3);
    }
    if (c < 32) {
      u16* w2 = (u16*)(smem + OFF_W2);
      int kk16 = tid >> 4, j2 = tid & 15;
      int hid2 = c * 16 + j2;
      for (int kk = kk16; kk < 1024; kk += 16) {
        int kb = kk >> 5, q2 = (kk >> 3) & 3, e = kk & 7;
        size_t dst = ((size_t)kb * 64 + q2 * 16 + j2) * 8 + e;
        float s = (kk < 512) ? p.Wxh[(size_t)kk * HID_ + hid2]
                             : p.Whh[(size_t)(kk - 512) * HID_ + hid2];
        w2[dst] = f2bf(s);
      }
      if (tid < 16) ((float*)(smem + OFF_B2))[tid] = p.bh[c * 16 + tid];
    }
    if (tid < 32) {
      int gt = tid >> 3, jj = tid & 7;
      ((float*)(smem + OFF_B1))[tid] = p.bg[gt][c * 8 + jj];
      ((float*)(smem + OFF_B3))[tid] = p.bg1[gt][c * 8 + jj];
    }
    // C / C1 state (fp32, LDS-resident, WG-local forever)
    float* Cs = (float*)(smem + OFF_C);
    float* C1s = (float*)(smem + OFF_C1);
    for (int it = 0; it < 2; it++) {
      int idx = tid + it * 256;
      int row = idx >> 3, j8 = idx & 7;
      float v = p.Cin[(size_t)(g * 64 + row) * HID_ + c * 8 + j8];
      Cs[row * 8 + j8] = v;
      C1s[row * 8 + j8] = v;
    }
  }
  // H / H1 state init (bf16 in ws), group-local rows
  for (int it = 0; it < 2; it++) {
    int idx = bi * 512 + tid + it * 256;
    u16 hv = f2bf(p.Hin[idx]);
    Hb0[idx] = hv;
    H1b[idx] = hv;
  }
  // Embedding gather, group-local: WG (g,c) fills Xe[t=4c..4c+3][g*64..+63][:]
  for (int tt = 0; tt < 4; tt++) {
    int t0 = c * 4 + tt;
    for (int pp = 0; pp < 16; pp++) {
      int b = g * 64 + w * 16 + pp;
      int tok = p.X[(size_t)b * Tt + t0];
      const float4* er = (const float4*)(p.E + (size_t)tok * EMB_);
      float4 v = er[lane];
      u16x4 u; u.x = f2bf(v.x); u.y = f2bf(v.y); u.z = f2bf(v.z); u.w = f2bf(v.w);
      *(u16x4*)(Xe + ((size_t)t0 * Bb + b) * EMB_ + lane * 4) = u;
    }
  }
  int ph = 0;
  groupbar(fl, c, ++ph);

  // ---- recurrent loop (group-local; groups drift independently) ----
  for (int t = 0; t < Tt; t++) {
    const u16* Xt = Xe + (size_t)t * Bb * EMB_;
    u16* Hsrc = (t & 1) ? Hb1 : Hb0;
    u16* Hdst = (t & 1) ? Hb0 : Hb1;

    // phase 1: cell 1  (reads Hsrc, writes Hdst)
    cell_phase(smem, OFF_W1, OFF_B1, OFF_C, Xt, Hsrc, Hdst, g, c, w, lane, tid);
    groupbar(fl, c, ++ph);

    // phase 2: H1mix = sigmoid(Hnew@W_xh + H1old@W_hh + b_h)   (WGs c<32, 16 cols each)
    if (c < 32) {
      const u16* h0 = Hdst + (size_t)(g * 64 + w * 16 + r) * HID_;
      const u16* h1 = H1b + (size_t)(g * 64 + w * 16 + r) * HID_;
      const u16* wb = (const u16*)(smem + OFF_W2) + lane * 8;
      f32x4 acc = {0.f, 0.f, 0.f, 0.f};
#pragma unroll
      for (int kb = 0; kb < 16; kb++) {
        s16x8 a = *(const s16x8*)(h0 + kb * 32 + q * 8);
        s16x8 b = *(const s16x8*)(wb + (size_t)kb * 512);
        acc = mfma16(a, b, acc);
      }
#pragma unroll
      for (int kb = 16; kb < 32; kb++) {
        s16x8 a = *(const s16x8*)(h1 + (kb - 16) * 32 + q * 8);
        s16x8 b = *(const s16x8*)(wb + (size_t)kb * 512);
        acc = mfma16(a, b, acc);
      }
      const float* b2 = (const float*)(smem + OFF_B2);
#pragma unroll
      for (int i = 0; i < 4; i++) {
        float v = sigm(acc[i] + b2[r]);
        H1m[(size_t)(g * 64 + w * 16 + q * 4 + i) * HID_ + c * 16 + r] = f2bf(v);
      }
    }
    groupbar(fl, c, ++ph);

    // phase 3: cell 2  (reads H1mix, writes H1b)
    cell_phase(smem, OFF_W3, OFF_B3, OFF_C1, Xt, H1m, H1b, g, c, w, lane, tid);
    groupbar(fl, c, ++ph);
  }

  // ---- all-groups done, then final: out = H1 @ W_hq + b_q (250 WGs x 128 cols) ----
  donebar(dn, bi);
  if (bi < 250) {
    const int n0 = bi * 128;
    u16* Wf = (u16*)smem;   // reuse weight LDS: [16 kb][8 nt][64 lane][8]
    for (int idx = tid; idx < 512 * 128; idx += NTHR) {
      int k = idx >> 7, nn2 = idx & 127;
      int nt = nn2 >> 4, rr = nn2 & 15;
      int kb = k >> 5, q2 = (k >> 3) & 3, e = k & 7;
      Wf[((size_t)(kb * 8 + nt) * 64 + q2 * 16 + rr) * 8 + e] =
          f2bf(p.Whq[(size_t)k * NCLS + n0 + nn2]);
    }
    float* bqs = (float*)(smem + OFF_C);
    if (tid < 128) bqs[tid] = p.bq[n0 + tid];
    __syncthreads();
    for (int mt = 0; mt < 4; mt++) {
      int rowb = mt * 64 + w * 16;
      const u16* arow = H1b + (size_t)(rowb + r) * HID_;
      f32x4 acc[8];
#pragma unroll
      for (int nt = 0; nt < 8; nt++) acc[nt] = (f32x4){0.f, 0.f, 0.f, 0.f};
      for (int kb = 0; kb < 16; kb++) {
        s16x8 a = *(const s16x8*)(arow + kb * 32 + q * 8);
#pragma unroll
        for (int nt = 0; nt < 8; nt++) {
          s16x8 b = *(const s16x8*)((const u16*)Wf + ((size_t)(kb * 8 + nt) * 64 + lane) * 8);
          acc[nt] = mfma16(a, b, acc[nt]);
        }
      }
#pragma unroll
      for (int nt = 0; nt < 8; nt++)
#pragma unroll
        for (int i = 0; i < 4; i++)
          p.out[(size_t)(rowb + q * 4 + i) * NCLS + n0 + nt * 16 + r] =
              acc[nt][i] + bqs[nt * 16 + r];
    }
  }
}

extern "C" void kernel_launch(void* const* d_in, const int* in_sizes, int n_in,
                              void* d_out, int out_size, void* d_ws, size_t ws_size,
                              hipStream_t stream) {
  (void)in_sizes; (void)n_in; (void)out_size; (void)ws_size;
  Params p;
  p.X   = (const int*)d_in[0];
  p.Hin = (const float*)d_in[1];
  p.Cin = (const float*)d_in[2];
  p.E   = (const float*)d_in[3];
  for (int gidx = 0; gidx < 4; gidx++) {   // gate order i,f,o,c
    int base = 4 + gidx * 6;
    p.Wx[gidx]  = (const float*)d_in[base + 0];
    p.Wh[gidx]  = (const float*)d_in[base + 1];
    p.bg[gidx]  = (const float*)d_in[base + 2];
    p.Wx1[gidx] = (const float*)d_in[base + 3];
    p.Wh1[gidx] = (const float*)d_in[base + 4];
    p.bg1[gidx] = (const float*)d_in[base + 5];
  }
  p.Wxh = (const float*)d_in[28];
  p.Whh = (const float*)d_in[29];
  p.bh  = (const float*)d_in[30];
  p.Whq = (const float*)d_in[31];
  p.bq  = (const float*)d_in[32];
  p.out = (float*)d_out;
  p.ws  = (char*)d_ws;

  hipFuncSetAttribute(reinterpret_cast<const void*>(lstm_pers),
                      hipFuncAttributeMaxDynamicSharedMemorySize, SMEM_BYTES);
  lstm_pers<<<dim3(NWG), dim3(NTHR), SMEM_BYTES, stream>>>(p);
}

// Round 3
// 8451.797 us; speedup vs baseline: 2.5793x; 1.6796x over previous
//
#include <hip/hip_runtime.h>
#include <cstdint>
#include <cstddef>

typedef unsigned short u16;
typedef unsigned long long u64;
typedef __attribute__((ext_vector_type(8))) short s16x8;
typedef __attribute__((ext_vector_type(4))) float f32x4;
typedef __attribute__((ext_vector_type(4))) unsigned short u16x4;

#define AGENT __HIP_MEMORY_SCOPE_AGENT

namespace {
constexpr int NWG  = 256;
constexpr int NTHR = 256;
constexpr int Bb   = 256;   // batch
constexpr int Tt   = 256;   // timesteps
constexpr int EMB_ = 256;
constexpr int HID_ = 512;
constexpr int NCLS = 32000;

// ---- LDS layout (bytes). B-operands stored in MFMA lane order:
//      elem addr = ((kb*NT + n)*64 + lane)*8 + e  -> ds_read_b128 lane-linear, 0 conflicts
constexpr int OFF_W1 = 0;                     // cell1 [24 kb][2 n][64 lane][8] = 49152 B
constexpr int OFF_W3 = 49152;                 // cell2, same shape
constexpr int OFF_W2 = 98304;                 // mix   [32 kb][1 n][64][8]     = 32768 B
constexpr int OFF_DS = 131072;                // gate scratch [64][33] f32 = 8448 B (final Wf reuses [0,131072))
constexpr int OFF_C  = 139520;                // C  state [64][8] f32 (bq reuse in final)
constexpr int OFF_C1 = 141568;                // C1 state
constexpr int OFF_B1 = 143616;
constexpr int OFF_B3 = 143744;
constexpr int OFF_B2 = 143872;
constexpr int SMEM_BYTES = 143936;            // 1 WG/CU

// ---- workspace layout (bytes) ----
constexpr size_t WS_FL   = 0;                         // 4 groups x 64 int flags
constexpr size_t WS_DONE = 1024;                      // 256 int done flags
constexpr size_t WS_HB0  = 2048;                      // H parity 0 [B][512] bf16
constexpr size_t WS_HB1  = WS_HB0 + (size_t)Bb * HID_ * 2;
constexpr size_t WS_H1   = WS_HB1 + (size_t)Bb * HID_ * 2;   // H1 state
constexpr size_t WS_HM   = WS_H1 + (size_t)Bb * HID_ * 2;    // H1mix
constexpr size_t WS_XE   = WS_HM + (size_t)Bb * HID_ * 2;    // Xe [T][B][EMB] bf16
}  // namespace

struct Params {
  const int* X; const float* Hin; const float* Cin; const float* E;
  const float* Wx[4];  const float* Wh[4];  const float* bg[4];   // cell 1 (i,f,o,c)
  const float* Wx1[4]; const float* Wh1[4]; const float* bg1[4];  // cell 2
  const float* Wxh; const float* Whh; const float* bh;
  const float* Whq; const float* bq;
  float* out; char* ws;
};

__device__ __forceinline__ u16 f2bf(float f) {
  union { float f; unsigned u; } v; v.f = f;
  unsigned r = v.u + 0x7FFFu + ((v.u >> 16) & 1u);
  return (u16)(r >> 16);
}
__device__ __forceinline__ float sigm(float x) { return 1.f / (1.f + __expf(-x)); }
__device__ __forceinline__ float tanh_(float x) {
  x = fminf(fmaxf(x, -10.f), 10.f);
  float e = __expf(-2.f * x);
  return (1.f - e) / (1.f + e);
}
__device__ __forceinline__ f32x4 mfma16(s16x8 a, s16x8 b, f32x4 c) {
  return __builtin_amdgcn_mfma_f32_16x16x32_bf16(a, b, c, 0, 0, 0);
}

// ---- LLC-coherent (sc0 sc1) data movement: relaxed agent atomics bypass L1/L2
// and are serviced at the memory-side Infinity Cache -> no wbl2/inv needed.
__device__ __forceinline__ void st8_llc(u16* p2, u64 v) {
  __hip_atomic_store((u64*)p2, v, __ATOMIC_RELAXED, AGENT);
}
__device__ __forceinline__ u64 ld8_llc(const u16* p2) {
  return __hip_atomic_load((const u64*)p2, __ATOMIC_RELAXED, AGENT);
}
__device__ __forceinline__ s16x8 ld16_llc(const u16* p2) {
  union { u64 q[2]; s16x8 v; } u;
  u.q[0] = ld8_llc(p2);
  u.q[1] = ld8_llc(p2 + 4);
  return u.v;
}

// Heavy barrier (release store + agent acquire fence -> wbl2/inv). Used ONCE
// after init (publishes normal-stored Xe/H-init) and once before final GEMM.
__device__ __forceinline__ void groupbar_heavy(int* fl, int slot, int ph) {
  __syncthreads();
  if (threadIdx.x == 0)
    __hip_atomic_store(&fl[slot], ph, __ATOMIC_RELEASE, AGENT);
  if (threadIdx.x < 64) {
    for (;;) {
      int v = __hip_atomic_load(&fl[threadIdx.x], __ATOMIC_RELAXED, AGENT);
      if (!__any(v < ph)) break;
      __builtin_amdgcn_s_sleep(1);
    }
  }
  __syncthreads();
  __builtin_amdgcn_fence(__ATOMIC_ACQUIRE, "agent");
}

// Light barrier: NO cache maintenance. Data traffic is all sc1 (LLC-coherent);
// __syncthreads drains vmcnt so all sc1 stores are LLC-acked before the flag.
__device__ __forceinline__ void groupbar_light(int* fl, int slot, int ph) {
  __syncthreads();
  if (threadIdx.x == 0)
    __hip_atomic_store(&fl[slot], ph, __ATOMIC_RELAXED, AGENT);
  if (threadIdx.x < 64) {
    for (;;) {
      int v = __hip_atomic_load(&fl[threadIdx.x], __ATOMIC_RELAXED, AGENT);
      if (!__any(v < ph)) break;
      __builtin_amdgcn_s_sleep(1);
    }
  }
  __syncthreads();
  __builtin_amdgcn_fence(__ATOMIC_ACQUIRE, "workgroup");  // compiler/order barrier, cheap
}

// One-time all-grid done wait (before the final GEMM). Heavy on purpose: its
// acquire-inv lets the final GEMM use normal cached loads on H1b.
__device__ __forceinline__ void donebar(int* dn, int bi) {
  __syncthreads();
  if (threadIdx.x == 0)
    __hip_atomic_store(&dn[bi], 1, __ATOMIC_RELEASE, AGENT);
  for (;;) {
    int v = __hip_atomic_load(&dn[threadIdx.x], __ATOMIC_RELAXED, AGENT);
    if (!__any(v < 1)) break;
    __builtin_amdgcn_s_sleep(1);
  }
  __syncthreads();
  __builtin_amdgcn_fence(__ATOMIC_ACQUIRE, "agent");
}

// One LSTM-cell phase: gates = [x_t | Hrec] @ Wlds (+bias) -> elementwise -> Hdst chunk.
// WG (g,c) computes rows g*64..+63, HID slice c*8..+7 for all 4 gates (N=32 cols).
// x_t reads: normal cached 16B (Xe immutable after heavy barrier, 64x L2 reuse).
// Hrec reads / Hdst writes: sc1 (LLC-coherent).
__device__ __forceinline__ void cell_phase(char* smem, int offW, int offB, int offC,
                                           const u16* Xt, const u16* Hrec, u16* Hdst,
                                           int g, int c, int w, int lane, int tid) {
  const int r = lane & 15, q = lane >> 4;
  const int row0 = w * 16;
  const u16* xrow = Xt + (size_t)(g * 64 + row0 + r) * EMB_;
  const u16* hrow = Hrec + (size_t)(g * 64 + row0 + r) * HID_;
  const u16* wb = (const u16*)(smem + offW) + lane * 8;
  f32x4 acc0 = {0.f, 0.f, 0.f, 0.f}, acc1 = {0.f, 0.f, 0.f, 0.f};
#pragma unroll
  for (int kb = 0; kb < 8; kb++) {                    // x_t part of K (256)
    s16x8 a  = *(const s16x8*)(xrow + kb * 32 + q * 8);
    s16x8 b0 = *(const s16x8*)(wb + (size_t)(kb * 2 + 0) * 512);
    s16x8 b1 = *(const s16x8*)(wb + (size_t)(kb * 2 + 1) * 512);
    acc0 = mfma16(a, b0, acc0);
    acc1 = mfma16(a, b1, acc1);
  }
#pragma unroll
  for (int kb = 8; kb < 24; kb++) {                   // recurrent part of K (512)
    s16x8 a  = ld16_llc(hrow + (kb - 8) * 32 + q * 8);
    s16x8 b0 = *(const s16x8*)(wb + (size_t)(kb * 2 + 0) * 512);
    s16x8 b1 = *(const s16x8*)(wb + (size_t)(kb * 2 + 1) * 512);
    acc0 = mfma16(a, b0, acc0);
    acc1 = mfma16(a, b1, acc1);
  }
  float* Ds = (float*)(smem + OFF_DS);
#pragma unroll
  for (int i = 0; i < 4; i++) {
    Ds[(row0 + q * 4 + i) * 33 + r]      = acc0[i];
    Ds[(row0 + q * 4 + i) * 33 + 16 + r] = acc1[i];
  }
  __syncthreads();
  const float* bs = (const float*)(smem + offB);
  float* Cs = (float*)(smem + offC);
  if (tid < 128) {                       // 128 threads x 4 contiguous hid -> 8B stores
    int row = tid >> 1, j0 = (tid & 1) * 4;
    union { u16 h[4]; u64 qv; } pk;
#pragma unroll
    for (int i = 0; i < 4; i++) {
      int j = j0 + i;
      float vi = Ds[row * 33 + 0 + j]  + bs[0 + j];
      float vf = Ds[row * 33 + 8 + j]  + bs[8 + j];
      float vo = Ds[row * 33 + 16 + j] + bs[16 + j];
      float vc = Ds[row * 33 + 24 + j] + bs[24 + j];
      float I = sigm(vi), F = sigm(vf), O = sigm(vo), Ct = tanh_(vc);
      float Cn = F * Cs[row * 8 + j] + I * Ct;
      Cs[row * 8 + j] = Cn;
      pk.h[i] = f2bf(O * tanh_(Cn));
    }
    st8_llc(Hdst + (size_t)(g * 64 + row) * HID_ + c * 8 + j0, pk.qv);
  }
}

__global__ __launch_bounds__(NTHR, 1) void lstm_pers(Params p) {
  extern __shared__ char smem[];
  const int tid = threadIdx.x;
  const int bi = blockIdx.x;
  const int w = tid >> 6, lane = tid & 63;
  const int g = bi >> 6, c = bi & 63;
  const int r = lane & 15, q = lane >> 4;

  int* fl = (int*)(p.ws + WS_FL) + g * 64;
  int* dn = (int*)(p.ws + WS_DONE);
  u16* Hb0 = (u16*)(p.ws + WS_HB0);
  u16* Hb1 = (u16*)(p.ws + WS_HB1);
  u16* H1b = (u16*)(p.ws + WS_H1);
  u16* H1m = (u16*)(p.ws + WS_HM);
  u16* Xe  = (u16*)(p.ws + WS_XE);

  // ---- one-time init: weights -> LDS (bf16, MFMA lane-order swizzle) ----
  {
    u16* w1 = (u16*)(smem + OFF_W1);
    u16* w3 = (u16*)(smem + OFF_W3);
    int gate = tid >> 6, kk8 = (tid >> 3) & 7, j = tid & 7;
    int cc = gate * 8 + j;          // col 0..31 (i0..7,f0..7,o0..7,c0..7)
    int n = cc >> 4, rr = cc & 15;
    int hid = c * 8 + j;
    for (int kk = kk8; kk < 768; kk += 8) {
      int kb = kk >> 5, q2 = (kk >> 3) & 3, e = kk & 7;
      size_t dst = ((size_t)(kb * 2 + n) * 64 + q2 * 16 + rr) * 8 + e;
      float s1 = (kk < 256) ? p.Wx[gate][(size_t)kk * HID_ + hid]
                            : p.Wh[gate][(size_t)(kk - 256) * HID_ + hid];
      float s3 = (kk < 256) ? p.Wx1[gate][(size_t)kk * HID_ + hid]
                            : p.Wh1[gate][(size_t)(kk - 256) * HID_ + hid];
      w1[dst] = f2bf(s1);
      w3[dst] = f2bf(s3);
    }
    if (c < 32) {
      u16* w2 = (u16*)(smem + OFF_W2);
      int kk16 = tid >> 4, j2 = tid & 15;
      int hid2 = c * 16 + j2;
      for (int kk = kk16; kk < 1024; kk += 16) {
        int kb = kk >> 5, q2 = (kk >> 3) & 3, e = kk & 7;
        size_t dst = ((size_t)kb * 64 + q2 * 16 + j2) * 8 + e;
        float s = (kk < 512) ? p.Wxh[(size_t)kk * HID_ + hid2]
                             : p.Whh[(size_t)(kk - 512) * HID_ + hid2];
        w2[dst] = f2bf(s);
      }
      if (tid < 16) ((float*)(smem + OFF_B2))[tid] = p.bh[c * 16 + tid];
    }
    if (tid < 32) {
      int gt = tid >> 3, jj = tid & 7;
      ((float*)(smem + OFF_B1))[tid] = p.bg[gt][c * 8 + jj];
      ((float*)(smem + OFF_B3))[tid] = p.bg1[gt][c * 8 + jj];
    }
    // C / C1 state (fp32, LDS-resident, WG-local forever)
    float* Cs = (float*)(smem + OFF_C);
    float* C1s = (float*)(smem + OFF_C1);
    for (int it = 0; it < 2; it++) {
      int idx = tid + it * 256;
      int row = idx >> 3, j8 = idx & 7;
      float v = p.Cin[(size_t)(g * 64 + row) * HID_ + c * 8 + j8];
      Cs[row * 8 + j8] = v;
      C1s[row * 8 + j8] = v;
    }
  }
  // H / H1 state init (bf16 in ws, normal stores -> published by heavy barrier)
  for (int it = 0; it < 2; it++) {
    int idx = bi * 512 + tid + it * 256;
    u16 hv = f2bf(p.Hin[idx]);
    Hb0[idx] = hv;
    H1b[idx] = hv;
  }
  // Embedding gather, group-local: WG (g,c) fills Xe[t=4c..4c+3][g*64..+63][:]
  for (int tt = 0; tt < 4; tt++) {
    int t0 = c * 4 + tt;
    for (int pp = 0; pp < 16; pp++) {
      int b = g * 64 + w * 16 + pp;
      int tok = p.X[(size_t)b * Tt + t0];
      const float4* er = (const float4*)(p.E + (size_t)tok * EMB_);
      float4 v = er[lane];
      u16x4 u; u.x = f2bf(v.x); u.y = f2bf(v.y); u.z = f2bf(v.z); u.w = f2bf(v.w);
      *(u16x4*)(Xe + ((size_t)t0 * Bb + b) * EMB_ + lane * 4) = u;
    }
  }
  int ph = 0;
  groupbar_heavy(fl, c, ++ph);   // publish init data (wbl2 dirty init lines BEFORE any sc1 store)

  // ---- recurrent loop (group-local; groups drift independently) ----
  for (int t = 0; t < Tt; t++) {
    const u16* Xt = Xe + (size_t)t * Bb * EMB_;
    u16* Hsrc = (t & 1) ? Hb1 : Hb0;
    u16* Hdst = (t & 1) ? Hb0 : Hb1;

    // phase 1: cell 1  (reads Hsrc, writes Hdst)
    cell_phase(smem, OFF_W1, OFF_B1, OFF_C, Xt, Hsrc, Hdst, g, c, w, lane, tid);
    groupbar_light(fl, c, ++ph);

    // phase 2: H1mix = sigmoid(Hnew@W_xh + H1old@W_hh + b_h)   (WGs c<32, 16 cols each)
    if (c < 32) {
      const u16* h0 = Hdst + (size_t)(g * 64 + w * 16 + r) * HID_;
      const u16* h1 = H1b + (size_t)(g * 64 + w * 16 + r) * HID_;
      const u16* wb = (const u16*)(smem + OFF_W2) + lane * 8;
      f32x4 acc = {0.f, 0.f, 0.f, 0.f};
#pragma unroll
      for (int kb = 0; kb < 16; kb++) {
        s16x8 a = ld16_llc(h0 + kb * 32 + q * 8);
        s16x8 b = *(const s16x8*)(wb + (size_t)kb * 512);
        acc = mfma16(a, b, acc);
      }
#pragma unroll
      for (int kb = 16; kb < 32; kb++) {
        s16x8 a = ld16_llc(h1 + (kb - 16) * 32 + q * 8);
        s16x8 b = *(const s16x8*)(wb + (size_t)kb * 512);
        acc = mfma16(a, b, acc);
      }
      float* Ds = (float*)(smem + OFF_DS);
#pragma unroll
      for (int i = 0; i < 4; i++)
        Ds[(w * 16 + q * 4 + i) * 33 + r] = acc[i];
      __syncthreads();
      const float* b2 = (const float*)(smem + OFF_B2);
      int row = tid >> 2, q4 = (tid & 3) * 4;
      union { u16 h[4]; u64 qv; } pk;
#pragma unroll
      for (int i = 0; i < 4; i++)
        pk.h[i] = f2bf(sigm(Ds[row * 33 + q4 + i] + b2[q4 + i]));
      st8_llc(H1m + (size_t)(g * 64 + row) * HID_ + c * 16 + q4, pk.qv);
    }
    groupbar_light(fl, c, ++ph);

    // phase 3: cell 2  (reads H1mix, writes H1b)
    cell_phase(smem, OFF_W3, OFF_B3, OFF_C1, Xt, H1m, H1b, g, c, w, lane, tid);
    groupbar_light(fl, c, ++ph);
  }

  // ---- all-groups done (heavy: acquire-inv), then final GEMM with cached loads ----
  donebar(dn, bi);
  if (bi < 250) {
    const int n0 = bi * 128;
    u16* Wf = (u16*)smem;   // reuse weight LDS: [16 kb][8 nt][64 lane][8]
    for (int idx = tid; idx < 512 * 128; idx += NTHR) {
      int k = idx >> 7, nn2 = idx & 127;
      int nt = nn2 >> 4, rr = nn2 & 15;
      int kb = k >> 5, q2 = (k >> 3) & 3, e = k & 7;
      Wf[((size_t)(kb * 8 + nt) * 64 + q2 * 16 + rr) * 8 + e] =
          f2bf(p.Whq[(size_t)k * NCLS + n0 + nn2]);
    }
    float* bqs = (float*)(smem + OFF_C);
    if (tid < 128) bqs[tid] = p.bq[n0 + tid];
    __syncthreads();
    for (int mt = 0; mt < 4; mt++) {
      int rowb = mt * 64 + w * 16;
      const u16* arow = H1b + (size_t)(rowb + r) * HID_;
      f32x4 acc[8];
#pragma unroll
      for (int nt = 0; nt < 8; nt++) acc[nt] = (f32x4){0.f, 0.f, 0.f, 0.f};
      for (int kb = 0; kb < 16; kb++) {
        s16x8 a = *(const s16x8*)(arow + kb * 32 + q * 8);
#pragma unroll
        for (int nt = 0; nt < 8; nt++) {
          s16x8 b = *(const s16x8*)((const u16*)Wf + ((size_t)(kb * 8 + nt) * 64 + lane) * 8);
          acc[nt] = mfma16(a, b, acc[nt]);
        }
      }
#pragma unroll
      for (int nt = 0; nt < 8; nt++)
#pragma unroll
        for (int i = 0; i < 4; i++)
          p.out[(size_t)(rowb + q * 4 + i) * NCLS + n0 + nt * 16 + r] =
              acc[nt][i] + bqs[nt * 16 + r];
    }
  }
}

extern "C" void kernel_launch(void* const* d_in, const int* in_sizes, int n_in,
                              void* d_out, int out_size, void* d_ws, size_t ws_size,
                              hipStream_t stream) {
  (void)in_sizes; (void)n_in; (void)out_size; (void)ws_size;
  Params p;
  p.X   = (const int*)d_in[0];
  p.Hin = (const float*)d_in[1];
  p.Cin = (const float*)d_in[2];
  p.E   = (const float*)d_in[3];
  for (int gidx = 0; gidx < 4; gidx++) {   // gate order i,f,o,c
    int base = 4 + gidx * 6;
    p.Wx[gidx]  = (const float*)d_in[base + 0];
    p.Wh[gidx]  = (const float*)d_in[base + 1];
    p.bg[gidx]  = (const float*)d_in[base + 2];
    p.Wx1[gidx] = (const float*)d_in[base + 3];
    p.Wh1[gidx] = (const float*)d_in[base + 4];
    p.bg1[gidx] = (const float*)d_in[base + 5];
  }
  p.Wxh = (const float*)d_in[28];
  p.Whh = (const float*)d_in[29];
  p.bh  = (const float*)d_in[30];
  p.Whq = (const float*)d_in[31];
  p.bq  = (const float*)d_in[32];
  p.out = (float*)d_out;
  p.ws  = (char*)d_ws;

  hipFuncSetAttribute(reinterpret_cast<const void*>(lstm_pers),
                      hipFuncAttributeMaxDynamicSharedMemorySize, SMEM_BYTES);
  lstm_pers<<<dim3(NWG), dim3(NTHR), SMEM_BYTES, stream>>>(p);
}

// Round 4
// 5369.213 us; speedup vs baseline: 4.0602x; 1.5741x over previous
//
#include <hip/hip_runtime.h>
#include <cstdint>
#include <cstddef>

typedef unsigned short u16;
typedef unsigned long long u64;
typedef __attribute__((ext_vector_type(8))) short s16x8;
typedef __attribute__((ext_vector_type(4))) float f32x4;
typedef __attribute__((ext_vector_type(4))) unsigned short u16x4;

#define AGENT __HIP_MEMORY_SCOPE_AGENT

namespace {
constexpr int NWG  = 256;
constexpr int NTHR = 256;
constexpr int Bb   = 256;   // batch
constexpr int Tt   = 256;   // timesteps
constexpr int EMB_ = 256;
constexpr int HID_ = 512;
constexpr int NCLS = 32000;

// ---- LDS layout (bytes). B-operands stored in MFMA lane order:
//      elem addr = ((kb*NT + n)*64 + lane)*8 + e  -> ds_read_b128 lane-linear, 0 conflicts
constexpr int OFF_W1 = 0;                     // cell1 [24 kb][2 n][64 lane][8] = 49152 B
constexpr int OFF_W3 = 49152;                 // cell2, same shape
constexpr int OFF_W2 = 98304;                 // mix   [32 kb][1 n][64][8]     = 32768 B
constexpr int OFF_DS = 131072;                // gate scratch [64][33] f32 = 8448 B (final Wf reuses [0,131072))
constexpr int OFF_C  = 139520;                // C  state [64][8] f32 (bq reuse in final)
constexpr int OFF_C1 = 141568;                // C1 state
constexpr int OFF_B1 = 143616;
constexpr int OFF_B3 = 143744;
constexpr int OFF_B2 = 143872;
constexpr int SMEM_BYTES = 143936;            // 1 WG/CU

// ---- workspace layout (bytes) ----
// flags padded: one 128B cache line per WG -> no hot-line store serialization
constexpr size_t WS_FL   = 0;                          // 256 WGs x 128 B = 32 KB
constexpr size_t WS_DONE = 32768;                      // 256 int done flags (one-time)
constexpr size_t WS_HB0  = 33792;                      // H parity 0 [B][512] bf16
constexpr size_t WS_HB1  = WS_HB0 + (size_t)Bb * HID_ * 2;
constexpr size_t WS_H1   = WS_HB1 + (size_t)Bb * HID_ * 2;   // H1 state
constexpr size_t WS_HM   = WS_H1 + (size_t)Bb * HID_ * 2;    // H1mix
constexpr size_t WS_XE   = WS_HM + (size_t)Bb * HID_ * 2;    // Xe [T][B][EMB] bf16
}  // namespace

struct Params {
  const int* X; const float* Hin; const float* Cin; const float* E;
  const float* Wx[4];  const float* Wh[4];  const float* bg[4];   // cell 1 (i,f,o,c)
  const float* Wx1[4]; const float* Wh1[4]; const float* bg1[4];  // cell 2
  const float* Wxh; const float* Whh; const float* bh;
  const float* Whq; const float* bq;
  float* out; char* ws;
};

__device__ __forceinline__ u16 f2bf(float f) {
  union { float f; unsigned u; } v; v.f = f;
  unsigned r = v.u + 0x7FFFu + ((v.u >> 16) & 1u);
  return (u16)(r >> 16);
}
__device__ __forceinline__ float sigm(float x) { return 1.f / (1.f + __expf(-x)); }
__device__ __forceinline__ float tanh_(float x) {
  x = fminf(fmaxf(x, -10.f), 10.f);
  float e = __expf(-2.f * x);
  return (1.f - e) / (1.f + e);
}
__device__ __forceinline__ f32x4 mfma16(s16x8 a, s16x8 b, f32x4 c) {
  return __builtin_amdgcn_mfma_f32_16x16x32_bf16(a, b, c, 0, 0, 0);
}

// ---- LLC-coherent (sc0 sc1) data movement: relaxed agent atomics bypass L1/L2
// and are serviced at the memory-side Infinity Cache -> no wbl2/inv needed.
__device__ __forceinline__ void st8_llc(u16* p2, u64 v) {
  __hip_atomic_store((u64*)p2, v, __ATOMIC_RELAXED, AGENT);
}
__device__ __forceinline__ u64 ld8_llc(const u16* p2) {
  return __hip_atomic_load((const u64*)p2, __ATOMIC_RELAXED, AGENT);
}
__device__ __forceinline__ s16x8 ld16_llc(const u16* p2) {
  union { u64 q[2]; s16x8 v; } u;
  u.q[0] = ld8_llc(p2);
  u.q[1] = ld8_llc(p2 + 4);
  return u.v;
}

// Heavy barrier (release store + agent acquire fence -> wbl2/inv). Used ONCE
// after init (publishes normal-stored Xe/H-init) and once before final GEMM.
// fl points at this group's padded flag array; flag i lives at fl[i*32].
__device__ __forceinline__ void groupbar_heavy(int* fl, int slot, int ph) {
  __syncthreads();
  if (threadIdx.x == 0)
    __hip_atomic_store(&fl[slot * 32], ph, __ATOMIC_RELEASE, AGENT);
  if (threadIdx.x < 64) {
    for (;;) {
      int v = __hip_atomic_load(&fl[threadIdx.x * 32], __ATOMIC_RELAXED, AGENT);
      if (!__any(v < ph)) break;
      __builtin_amdgcn_s_sleep(1);
    }
  }
  __syncthreads();
  __builtin_amdgcn_fence(__ATOMIC_ACQUIRE, "agent");
}

// Light barrier: NO cache maintenance. Data traffic is all sc1 (LLC-coherent);
// __syncthreads drains vmcnt so all sc1 stores are LLC-acked before the flag.
__device__ __forceinline__ void groupbar_light(int* fl, int slot, int ph) {
  __syncthreads();
  if (threadIdx.x == 0)
    __hip_atomic_store(&fl[slot * 32], ph, __ATOMIC_RELAXED, AGENT);
  if (threadIdx.x < 64) {
    for (;;) {
      int v = __hip_atomic_load(&fl[threadIdx.x * 32], __ATOMIC_RELAXED, AGENT);
      if (!__any(v < ph)) break;
      __builtin_amdgcn_s_sleep(1);
    }
  }
  __syncthreads();
  __builtin_amdgcn_fence(__ATOMIC_ACQUIRE, "workgroup");  // compiler/order barrier, cheap
}

// One-time all-grid done wait (before the final GEMM). Heavy on purpose: its
// acquire-inv lets the final GEMM use normal cached loads on H1b.
__device__ __forceinline__ void donebar(int* dn, int bi) {
  __syncthreads();
  if (threadIdx.x == 0)
    __hip_atomic_store(&dn[bi], 1, __ATOMIC_RELEASE, AGENT);
  for (;;) {
    int v = __hip_atomic_load(&dn[threadIdx.x], __ATOMIC_RELAXED, AGENT);
    if (!__any(v < 1)) break;
    __builtin_amdgcn_s_sleep(1);
  }
  __syncthreads();
  __builtin_amdgcn_fence(__ATOMIC_ACQUIRE, "agent");
}

// One LSTM-cell phase: gates = [x_t | Hrec] @ Wlds (+bias) -> elementwise -> Hdst chunk.
// WG (g,c) computes rows g*64..+63, HID slice c*8..+7 for all 4 gates (N=32 cols).
// x_t reads: normal cached 16B (Xe immutable after heavy barrier, 64x L2 reuse).
// Hrec reads / Hdst writes: sc1 (LLC-coherent).
__device__ __forceinline__ void cell_phase(char* smem, int offW, int offB, int offC,
                                           const u16* Xt, const u16* Hrec, u16* Hdst,
                                           int g, int c, int w, int lane, int tid) {
  const int r = lane & 15, q = lane >> 4;
  const int row0 = w * 16;
  const u16* xrow = Xt + (size_t)(g * 64 + row0 + r) * EMB_;
  const u16* hrow = Hrec + (size_t)(g * 64 + row0 + r) * HID_;
  const u16* wb = (const u16*)(smem + offW) + lane * 8;
  f32x4 acc0 = {0.f, 0.f, 0.f, 0.f}, acc1 = {0.f, 0.f, 0.f, 0.f};
#pragma unroll
  for (int kb = 0; kb < 8; kb++) {                    // x_t part of K (256)
    s16x8 a  = *(const s16x8*)(xrow + kb * 32 + q * 8);
    s16x8 b0 = *(const s16x8*)(wb + (size_t)(kb * 2 + 0) * 512);
    s16x8 b1 = *(const s16x8*)(wb + (size_t)(kb * 2 + 1) * 512);
    acc0 = mfma16(a, b0, acc0);
    acc1 = mfma16(a, b1, acc1);
  }
#pragma unroll
  for (int kb = 8; kb < 24; kb++) {                   // recurrent part of K (512)
    s16x8 a  = ld16_llc(hrow + (kb - 8) * 32 + q * 8);
    s16x8 b0 = *(const s16x8*)(wb + (size_t)(kb * 2 + 0) * 512);
    s16x8 b1 = *(const s16x8*)(wb + (size_t)(kb * 2 + 1) * 512);
    acc0 = mfma16(a, b0, acc0);
    acc1 = mfma16(a, b1, acc1);
  }
  float* Ds = (float*)(smem + OFF_DS);
#pragma unroll
  for (int i = 0; i < 4; i++) {
    Ds[(row0 + q * 4 + i) * 33 + r]      = acc0[i];
    Ds[(row0 + q * 4 + i) * 33 + 16 + r] = acc1[i];
  }
  __syncthreads();
  const float* bs = (const float*)(smem + offB);
  float* Cs = (float*)(smem + offC);
  if (tid < 128) {                       // 128 threads x 4 contiguous hid -> 8B stores
    int row = tid >> 1, j0 = (tid & 1) * 4;
    union { u16 h[4]; u64 qv; } pk;
#pragma unroll
    for (int i = 0; i < 4; i++) {
      int j = j0 + i;
      float vi = Ds[row * 33 + 0 + j]  + bs[0 + j];
      float vf = Ds[row * 33 + 8 + j]  + bs[8 + j];
      float vo = Ds[row * 33 + 16 + j] + bs[16 + j];
      float vc = Ds[row * 33 + 24 + j] + bs[24 + j];
      float I = sigm(vi), F = sigm(vf), O = sigm(vo), Ct = tanh_(vc);
      float Cn = F * Cs[row * 8 + j] + I * Ct;
      Cs[row * 8 + j] = Cn;
      pk.h[i] = f2bf(O * tanh_(Cn));
    }
    st8_llc(Hdst + (size_t)(g * 64 + row) * HID_ + c * 8 + j0, pk.qv);
  }
}

__global__ __launch_bounds__(NTHR, 1) void lstm_pers(Params p) {
  extern __shared__ char smem[];
  const int tid = threadIdx.x;
  const int bi = blockIdx.x;
  const int w = tid >> 6, lane = tid & 63;
  const int g = bi >> 6, c = bi & 63;
  const int r = lane & 15, q = lane >> 4;

  int* fl = (int*)(p.ws + WS_FL) + g * 64 * 32;   // padded: one line per WG
  int* dn = (int*)(p.ws + WS_DONE);
  u16* Hb0 = (u16*)(p.ws + WS_HB0);
  u16* Hb1 = (u16*)(p.ws + WS_HB1);
  u16* H1b = (u16*)(p.ws + WS_H1);
  u16* H1m = (u16*)(p.ws + WS_HM);
  u16* Xe  = (u16*)(p.ws + WS_XE);

  // ---- one-time init: weights -> LDS (bf16, MFMA lane-order swizzle) ----
  {
    u16* w1 = (u16*)(smem + OFF_W1);
    u16* w3 = (u16*)(smem + OFF_W3);
    int gate = tid >> 6, kk8 = (tid >> 3) & 7, j = tid & 7;
    int cc = gate * 8 + j;          // col 0..31 (i0..7,f0..7,o0..7,c0..7)
    int n = cc >> 4, rr = cc & 15;
    int hid = c * 8 + j;
    for (int kk = kk8; kk < 768; kk += 8) {
      int kb = kk >> 5, q2 = (kk >> 3) & 3, e = kk & 7;
      size_t dst = ((size_t)(kb * 2 + n) * 64 + q2 * 16 + rr) * 8 + e;
      float s1 = (kk < 256) ? p.Wx[gate][(size_t)kk * HID_ + hid]
                            : p.Wh[gate][(size_t)(kk - 256) * HID_ + hid];
      float s3 = (kk < 256) ? p.Wx1[gate][(size_t)kk * HID_ + hid]
                            : p.Wh1[gate][(size_t)(kk - 256) * HID_ + hid];
      w1[dst] = f2bf(s1);
      w3[dst] = f2bf(s3);
    }
    {  // mix weights: every WG holds cols (c>>1)*16..+15 (pairs share)
      u16* w2 = (u16*)(smem + OFF_W2);
      int kk16 = tid >> 4, j2 = tid & 15;
      int hid2 = (c >> 1) * 16 + j2;
      for (int kk = kk16; kk < 1024; kk += 16) {
        int kb = kk >> 5, q2 = (kk >> 3) & 3, e = kk & 7;
        size_t dst = ((size_t)kb * 64 + q2 * 16 + j2) * 8 + e;
        float s = (kk < 512) ? p.Wxh[(size_t)kk * HID_ + hid2]
                             : p.Whh[(size_t)(kk - 512) * HID_ + hid2];
        w2[dst] = f2bf(s);
      }
      if (tid < 16) ((float*)(smem + OFF_B2))[tid] = p.bh[(c >> 1) * 16 + tid];
    }
    if (tid < 32) {
      int gt = tid >> 3, jj = tid & 7;
      ((float*)(smem + OFF_B1))[tid] = p.bg[gt][c * 8 + jj];
      ((float*)(smem + OFF_B3))[tid] = p.bg1[gt][c * 8 + jj];
    }
    // C / C1 state (fp32, LDS-resident, WG-local forever)
    float* Cs = (float*)(smem + OFF_C);
    float* C1s = (float*)(smem + OFF_C1);
    for (int it = 0; it < 2; it++) {
      int idx = tid + it * 256;
      int row = idx >> 3, j8 = idx & 7;
      float v = p.Cin[(size_t)(g * 64 + row) * HID_ + c * 8 + j8];
      Cs[row * 8 + j8] = v;
      C1s[row * 8 + j8] = v;
    }
  }
  // H / H1 state init (bf16 in ws, normal stores -> published by heavy barrier)
  for (int it = 0; it < 2; it++) {
    int idx = bi * 512 + tid + it * 256;
    u16 hv = f2bf(p.Hin[idx]);
    Hb0[idx] = hv;
    H1b[idx] = hv;
  }
  // Embedding gather, group-local: WG (g,c) fills Xe[t=4c..4c+3][g*64..+63][:]
  for (int tt = 0; tt < 4; tt++) {
    int t0 = c * 4 + tt;
    for (int pp = 0; pp < 16; pp++) {
      int b = g * 64 + w * 16 + pp;
      int tok = p.X[(size_t)b * Tt + t0];
      const float4* er = (const float4*)(p.E + (size_t)tok * EMB_);
      float4 v = er[lane];
      u16x4 u; u.x = f2bf(v.x); u.y = f2bf(v.y); u.z = f2bf(v.z); u.w = f2bf(v.w);
      *(u16x4*)(Xe + ((size_t)t0 * Bb + b) * EMB_ + lane * 4) = u;
    }
  }
  int ph = 0;
  groupbar_heavy(fl, c, ++ph);   // publish init data (wbl2 dirty init lines BEFORE any sc1 store)

  // ---- recurrent loop (group-local; groups drift independently) ----
  for (int t = 0; t < Tt; t++) {
    const u16* Xt = Xe + (size_t)t * Bb * EMB_;
    u16* Hsrc = (t & 1) ? Hb1 : Hb0;
    u16* Hdst = (t & 1) ? Hb0 : Hb1;

    // phase 1: cell 1  (reads Hsrc, writes Hdst)
    cell_phase(smem, OFF_W1, OFF_B1, OFF_C, Xt, Hsrc, Hdst, g, c, w, lane, tid);
    groupbar_light(fl, c, ++ph);

    // phase 2: H1mix = sigmoid(Hnew@W_xh + H1old@W_hh + b_h)
    // all 64 WGs: pair-split -> cols (c>>1)*16..+15, rows (c&1)*32..+31
    {
      float* Ds = (float*)(smem + OFF_DS);
      if (w < 2) {
        int rbase = g * 64 + (c & 1) * 32 + w * 16 + r;
        const u16* h0 = Hdst + (size_t)rbase * HID_;
        const u16* h1 = H1b + (size_t)rbase * HID_;
        const u16* wb = (const u16*)(smem + OFF_W2) + lane * 8;
        f32x4 acc = {0.f, 0.f, 0.f, 0.f};
#pragma unroll
        for (int kb = 0; kb < 16; kb++) {
          s16x8 a = ld16_llc(h0 + kb * 32 + q * 8);
          s16x8 b = *(const s16x8*)(wb + (size_t)kb * 512);
          acc = mfma16(a, b, acc);
        }
#pragma unroll
        for (int kb = 16; kb < 32; kb++) {
          s16x8 a = ld16_llc(h1 + (kb - 16) * 32 + q * 8);
          s16x8 b = *(const s16x8*)(wb + (size_t)kb * 512);
          acc = mfma16(a, b, acc);
        }
#pragma unroll
        for (int i = 0; i < 4; i++)
          Ds[(w * 16 + q * 4 + i) * 17 + r] = acc[i];
      }
      __syncthreads();
      if (tid < 128) {
        const float* b2 = (const float*)(smem + OFF_B2);
        int row = tid >> 2, j0 = (tid & 3) * 4;
        union { u16 h[4]; u64 qv; } pk;
#pragma unroll
        for (int i = 0; i < 4; i++)
          pk.h[i] = f2bf(sigm(Ds[row * 17 + j0 + i] + b2[j0 + i]));
        st8_llc(H1m + (size_t)(g * 64 + (c & 1) * 32 + row) * HID_ + (c >> 1) * 16 + j0,
                pk.qv);
      }
    }
    groupbar_light(fl, c, ++ph);

    // phase 3: cell 2  (reads H1mix, writes H1b)
    cell_phase(smem, OFF_W3, OFF_B3, OFF_C1, Xt, H1m, H1b, g, c, w, lane, tid);
    groupbar_light(fl, c, ++ph);
  }

  // ---- all-groups done (heavy: acquire-inv), then final GEMM with cached loads ----
  donebar(dn, bi);
  if (bi < 250) {
    const int n0 = bi * 128;
    u16* Wf = (u16*)smem;   // reuse weight LDS: [16 kb][8 nt][64 lane][8]
    for (int idx = tid; idx < 512 * 128; idx += NTHR) {
      int k = idx >> 7, nn2 = idx & 127;
      int nt = nn2 >> 4, rr = nn2 & 15;
      int kb = k >> 5, q2 = (k >> 3) & 3, e = k & 7;
      Wf[((size_t)(kb * 8 + nt) * 64 + q2 * 16 + rr) * 8 + e] =
          f2bf(p.Whq[(size_t)k * NCLS + n0 + nn2]);
    }
    float* bqs = (float*)(smem + OFF_C);
    if (tid < 128) bqs[tid] = p.bq[n0 + tid];
    __syncthreads();
    for (int mt = 0; mt < 4; mt++) {
      int rowb = mt * 64 + w * 16;
      const u16* arow = H1b + (size_t)(rowb + r) * HID_;
      f32x4 acc[8];
#pragma unroll
      for (int nt = 0; nt < 8; nt++) acc[nt] = (f32x4){0.f, 0.f, 0.f, 0.f};
      for (int kb = 0; kb < 16; kb++) {
        s16x8 a = *(const s16x8*)(arow + kb * 32 + q * 8);
#pragma unroll
        for (int nt = 0; nt < 8; nt++) {
          s16x8 b = *(const s16x8*)((const u16*)Wf + ((size_t)(kb * 8 + nt) * 64 + lane) * 8);
          acc[nt] = mfma16(a, b, acc[nt]);
        }
      }
#pragma unroll
      for (int nt = 0; nt < 8; nt++)
#pragma unroll
        for (int i = 0; i < 4; i++)
          p.out[(size_t)(rowb + q * 4 + i) * NCLS + n0 + nt * 16 + r] =
              acc[nt][i] + bqs[nt * 16 + r];
    }
  }
}

extern "C" void kernel_launch(void* const* d_in, const int* in_sizes, int n_in,
                              void* d_out, int out_size, void* d_ws, size_t ws_size,
                              hipStream_t stream) {
  (void)in_sizes; (void)n_in; (void)out_size; (void)ws_size;
  Params p;
  p.X   = (const int*)d_in[0];
  p.Hin = (const float*)d_in[1];
  p.Cin = (const float*)d_in[2];
  p.E   = (const float*)d_in[3];
  for (int gidx = 0; gidx < 4; gidx++) {   // gate order i,f,o,c
    int base = 4 + gidx * 6;
    p.Wx[gidx]  = (const float*)d_in[base + 0];
    p.Wh[gidx]  = (const float*)d_in[base + 1];
    p.bg[gidx]  = (const float*)d_in[base + 2];
    p.Wx1[gidx] = (const float*)d_in[base + 3];
    p.Wh1[gidx] = (const float*)d_in[base + 4];
    p.bg1[gidx] = (const float*)d_in[base + 5];
  }
  p.Wxh = (const float*)d_in[28];
  p.Whh = (const float*)d_in[29];
  p.bh  = (const float*)d_in[30];
  p.Whq = (const float*)d_in[31];
  p.bq  = (const float*)d_in[32];
  p.out = (float*)d_out;
  p.ws  = (char*)d_ws;

  hipFuncSetAttribute(reinterpret_cast<const void*>(lstm_pers),
                      hipFuncAttributeMaxDynamicSharedMemorySize, SMEM_BYTES);
  lstm_pers<<<dim3(NWG), dim3(NTHR), SMEM_BYTES, stream>>>(p);
}